// Round 8
// baseline (219.073 us; speedup 1.0000x reference)
//
#include <hip/hip_runtime.h>
#include <hip/hip_bf16.h>
#include <math.h>

// MHA B=8,S=2048,D=512,H=8,LAT=64,OUT=64. fp32 in/out.
// R21 == R20 resubmit (container failed twice; no data). qkv rebuilt async:
//  - NEW xprep: x fp32 -> bf16 Xb ONCE (Xb aliases Ob: dead until flash writes)
//  - qkv: x-tile via global_load_lds (dbuf, XOR-chunk swizzle = verified flash
//    pattern, 0 conflicts), W direct global->VGPR (L2-hot, never touches LDS),
//    ONE vmcnt(0)+barrier per K-step, 24 MFMA/barrier, LDS 25.6KB ->
//    4 blocks/CU (16 waves). MFMA order + sigma-VT epilogue element-identical
//    to R17 -> bit-identical output.
// flash (R19) / out / wprep unchanged.
static constexpr int Bn = 8, Sn = 2048, Dn = 512, Hn = 8, LATn = 64, OUTn = 64;

typedef short  bf16x8 __attribute__((ext_vector_type(8)));
typedef float  f32x4  __attribute__((ext_vector_type(4)));

__device__ __forceinline__ unsigned short f2bf(float f) {   // RNE (prep kernels)
    union { float f; unsigned int i; } v; v.f = f;
    unsigned int x = v.i;
    return (unsigned short)((x + 0x7FFFu + ((x >> 16) & 1u)) >> 16);
}
// pack two floats -> two bf16 (round-half-up: bias 2^-17 rel, ~RNE quality)
__device__ __forceinline__ unsigned int pack2bf(float a, float b) {
    unsigned int ua = __float_as_uint(a) + 0x8000u;
    unsigned int ub = __float_as_uint(b) + 0x8000u;
    return (ua >> 16) | (ub & 0xFFFF0000u);
}
// HW packed f32->bf16 (RNE), low16=cvt(a) high16=cvt(b)
__device__ __forceinline__ unsigned int cvtpk(float a, float b) {
    unsigned int r;
    asm("v_cvt_pk_bf16_f32 %0, %1, %2" : "=v"(r) : "v"(a), "v"(b));
    return r;
}

#if __has_builtin(__builtin_amdgcn_exp2f)
#define EXP2(x) __builtin_amdgcn_exp2f(x)
#else
#define EXP2(x) exp2f(x)
#endif

// async 16B global->LDS; vmcnt-tracked; LDS dest = wave-uniform base + lane*16
__device__ __forceinline__ void gl_lds16(const void* g, void* l) {
    __builtin_amdgcn_global_load_lds(
        (const __attribute__((address_space(1))) unsigned int*)g,
        (__attribute__((address_space(3))) unsigned int*)l, 16, 0, 0);
}

// ---------------- Kernel 0a: x fp32 -> bf16 (once; Xb aliases Ob) -----------
__global__ __launch_bounds__(256) void xprep(
    const float* __restrict__ x, unsigned short* __restrict__ Xb)
{
    const size_t base = ((size_t)blockIdx.x * 256 + threadIdx.x) * 16;
    const float* src = x + base;
    float4 u0 = *(const float4*)(src);
    float4 u1 = *(const float4*)(src + 4);
    float4 u2 = *(const float4*)(src + 8);
    float4 u3 = *(const float4*)(src + 12);
    unsigned int pk[8] = { pack2bf(u0.x,u0.y), pack2bf(u0.z,u0.w),
                           pack2bf(u1.x,u1.y), pack2bf(u1.z,u1.w),
                           pack2bf(u2.x,u2.y), pack2bf(u2.z,u2.w),
                           pack2bf(u3.x,u3.y), pack2bf(u3.z,u3.w) };
    *(bf16x8*)(Xb + base)     = *(bf16x8*)(pk);
    *(bf16x8*)(Xb + base + 8) = *(bf16x8*)(pk + 4);
}

// ---------------- Kernel 0b: weight prep ------------------------------------
// WT[h][192][512] bf16 (Q slice scaled by 0.125*log2e), then WOT[64][512].
__global__ __launch_bounds__(256) void wprep(
    const float* __restrict__ WQ, const float* __restrict__ WK,
    const float* __restrict__ WV, const float* __restrict__ WO,
    unsigned short* __restrict__ WT)
{
    __shared__ float tile[64][65];
    const int t  = threadIdx.x;
    const int d0 = blockIdx.x * 64;
    const int yy = blockIdx.y;

    const float* W; float scale = 1.0f; size_t dstbase;
    if (yy < 24) {
        int h = yy / 3, which = yy % 3;
        W = (which == 0) ? WQ : (which == 1) ? WK : WV;
        W += (size_t)h * Dn * 64;
        if (which == 0) scale = 0.125f * 1.44269504088896f;   // fold 1/8 * log2(e)
        dstbase = ((size_t)h * 192 + which * 64) * Dn;
    } else {
        W = WO;                                                // [512][64]
        dstbase = (size_t)8 * 192 * Dn;                        // WOT after QKV
    }

    for (int i = 0; i < 4; ++i) {
        int idx = i * 256 + t;
        int r = idx >> 4, c = (idx & 15) * 4;
        float4 u = *(const float4*)(W + (size_t)(d0 + r) * 64 + c);
        tile[r][c] = u.x; tile[r][c+1] = u.y; tile[r][c+2] = u.z; tile[r][c+3] = u.w;
    }
    __syncthreads();
    const int n = t & 63, dd = t >> 6;
    unsigned short pk[16];
    for (int i = 0; i < 16; ++i) pk[i] = f2bf(tile[dd*16 + i][n] * scale);
    size_t dst = dstbase + (size_t)n * Dn + d0 + dd * 16;
    *(bf16x8*)(WT + dst)     = *(bf16x8*)(pk);
    *(bf16x8*)(WT + dst + 8) = *(bf16x8*)(pk + 8);
}

// ---------------- Kernel 1: MFMA QKV projection (R20 async rebuild) ---------
// Block = (s-tile 64, bh). x-tile from Xb via global_load_lds (dbuf, XOR chunk
// swizzle); W fragments direct global->VGPR; one vmcnt(0)+barrier per K-step.
// Values/order element-identical to R17 -> bit-identical Qb/Kb/VT.
__global__ __launch_bounds__(256, 4) void qkv_mfma(
    const unsigned short* __restrict__ Xb, const unsigned short* __restrict__ WT,
    unsigned short* __restrict__ Qb, unsigned short* __restrict__ Kb,
    unsigned short* __restrict__ VT)
{
    __shared__ __align__(16) unsigned short lds[64 * 200];   // 25.6 KB
    unsigned short* L = lds;                                  // epilogue view
    // staging view: Xs[buf] = lds + 4096*buf (64 rows x 8 chunks x 8 shorts)

    const int t  = threadIdx.x;
    const int w  = t >> 6, ln = t & 63;
    const int nl = ln & 15, g = ln >> 4;
    const int bh = blockIdx.y, b = bh >> 3, h = bh & 7;
    const int s0 = blockIdx.x * 64;

    // x staging: thread t owns chunks t and 256+t of the 512-chunk tile.
    // lds chunk (r,c) holds global chunk (r, c^(r&7))  [verified flash pattern]
    const int r0 = t >> 3,      sc0 = (t & 7) ^ (r0 & 7);
    const int r1 = 32 + (t>>3), sc1 = (t & 7) ^ (r1 & 7);
    const unsigned short* xg0 = Xb + ((size_t)(b * Sn + s0 + r0)) * Dn + sc0 * 8;
    const unsigned short* xg1 = Xb + ((size_t)(b * Sn + s0 + r1)) * Dn + sc1 * 8;

    // A-fragment read offsets (swizzled), row = 16m+nl, chunk (4kc+g)^(nl&7)
    const int p = nl & 7;
    const int aoff0 = nl * 64 + 8 * ((g    ) ^ p);
    const int aoff1 = nl * 64 + 8 * ((4 + g) ^ p);

    // W direct-load lane base: row 48w+16j+nl, cols k0+32kc+8g
    const unsigned short* wb = WT + ((size_t)h * 192 + 48 * w + nl) * Dn + 8 * g;

    f32x4 acc[4][3];
    for (int m = 0; m < 4; ++m)
        for (int j = 0; j < 3; ++j) acc[m][j] = (f32x4){0.f, 0.f, 0.f, 0.f};

    // prologue: stage x k-slice 0 into buf 0
    gl_lds16(xg0, lds + 512 * w);
    gl_lds16(xg1, lds + 2048 + 512 * w);

    for (int kt = 0; kt < 8; ++kt) {
        asm volatile("s_waitcnt vmcnt(0)" ::: "memory");
        __builtin_amdgcn_s_barrier();
        if (kt < 7) {                              // stage next slice (async)
            unsigned short* dst = lds + 4096 * ((kt + 1) & 1);
            gl_lds16(xg0 + (kt + 1) * 64, dst + 512 * w);
            gl_lds16(xg1 + (kt + 1) * 64, dst + 2048 + 512 * w);
        }
        const unsigned short* cur = lds + 4096 * (kt & 1);
        const int k0 = kt * 64;

        bf16x8 bb[3][2];                           // W frags, global->VGPR
        #pragma unroll
        for (int j = 0; j < 3; ++j) {
            bb[j][0] = *(const bf16x8*)(wb + j * 8192 + k0);
            bb[j][1] = *(const bf16x8*)(wb + j * 8192 + k0 + 32);
        }
        #pragma unroll
        for (int kc = 0; kc < 2; ++kc) {
            bf16x8 a[4];
            #pragma unroll
            for (int m = 0; m < 4; ++m)
                a[m] = *(const bf16x8*)(cur + (kc ? aoff1 : aoff0) + m * 1024);
            #pragma unroll
            for (int m = 0; m < 4; ++m)
                #pragma unroll
                for (int j = 0; j < 3; ++j)
                    acc[m][j] = __builtin_amdgcn_mfma_f32_16x16x32_bf16(
                                    a[m], bb[j][kc], acc[m][j], 0, 0, 0);
        }
    }
    __syncthreads();
    for (int m = 0; m < 4; ++m)                    // C: col=lane&15, row=4g+reg
        for (int j = 0; j < 3; ++j) {
            int n = 48*w + 16*j + nl;
            for (int r = 0; r < 4; ++r)
                L[(16*m + 4*g + r)*200 + n] = f2bf(acc[m][j][r]);
        }
    __syncthreads();
    for (int i = 0; i < 4; ++i) {                  // Qb/Kb row-major
        int idx = i * 256 + t;
        int r = idx >> 4, c = (idx & 15) * 8;
        bf16x8 v = *(const bf16x8*)(L + r*200 + c);
        size_t o = ((size_t)bh * Sn + s0 + r) * 64;
        if (c < 64) *(bf16x8*)(Qb + o + c)      = v;
        else        *(bf16x8*)(Kb + o + c - 64) = v;
    }
    {   // VT[bh][o][s], sigma k-permuted within 32-blocks (for in-reg P in flash)
        int o = t & 63, cc = t >> 6;
        unsigned short pk[16];
        for (int i = 0; i < 16; ++i) {
            int srow = 32*(cc>>1) + 16*((i>>2)&1) + 8*(cc&1) + 4*((i>>3)&1) + (i&3);
            pk[i] = L[srow*200 + 128 + o];
        }
        size_t dst = ((size_t)bh * 64 + o) * Sn + s0 + 16*cc;
        *(bf16x8*)(VT + dst)     = *(bf16x8*)(pk);
        *(bf16x8*)(VT + dst + 8) = *(bf16x8*)(pk + 8);
    }
}

// ---------------- Kernel 2: MFMA flash attention (R19, unchanged) -----------
// 8 waves x 32 q-rows (2 q-sets), 256 q/block, grid (8,64)=2 blocks/CU.
// In-register P (sigma-permuted V). 3-buffer KV, depth-2 prefetch,
// one s_barrier/tile, vmcnt(2) counted. setprio on MFMA.
__global__ __launch_bounds__(512, 4) void flash_mfma(
    const unsigned short* __restrict__ Qb,
    const unsigned short* __restrict__ Kb,
    const unsigned short* __restrict__ VT,
    unsigned short* __restrict__ Ob)
{
    __shared__ __align__(16) unsigned short KV[3][2][4096];   // 48 KB

    const int t  = threadIdx.x;                    // 512 threads, 8 waves
    const int w  = t >> 6, ln = t & 63;
    const int qh = ln & 15, g = (ln >> 4) & 3;
    const int bh = blockIdx.y, b = bh >> 3, h = bh & 7;
    const int q0 = blockIdx.x * 256;
    const int qw = q0 + 32 * w;                    // this wave's 32 q rows

    bf16x8 bq[2][2];
    #pragma unroll
    for (int qs = 0; qs < 2; ++qs) {
        const unsigned short* qp =
            Qb + ((size_t)bh * Sn + qw + 16*qs + qh) * 64 + 8*g;
        bq[qs][0] = *(const bf16x8*)(qp);
        bq[qs][1] = *(const bf16x8*)(qp + 32);
    }

    const int r0 = t >> 3;                         // tile row 0..63
    const int cs = (t & 7) ^ (r0 & 7);             // swizzled source chunk col
    const unsigned short* kg = Kb + ((size_t)bh * Sn + r0) * 64 + cs * 8;
    const unsigned short* vg = VT + ((size_t)bh * 64 + r0) * Sn + cs * 8;

    const int koff0 = qh*64 + (((g    ) ^ (qh & 7)) * 8);
    const int koff1 = qh*64 + (((4 + g) ^ (qh & 7)) * 8);

    f32x4 o_acc[2][4];
    #pragma unroll
    for (int qs = 0; qs < 2; ++qs)
        #pragma unroll
        for (int f = 0; f < 4; ++f) o_acc[qs][f] = (f32x4){0.f, 0.f, 0.f, 0.f};
    float l_run[2] = {0.f, 0.f};

    gl_lds16(kg,        &KV[0][0][w * 512]);
    gl_lds16(vg,        &KV[0][1][w * 512]);
    gl_lds16(kg + 4096, &KV[1][0][w * 512]);
    gl_lds16(vg + 64,   &KV[1][1][w * 512]);

    constexpr int NT = Sn / 64;                    // 32 tiles
    int buf = 0, sbuf = 2;
    for (int kt = 0; kt < NT; ++kt) {
        if (kt < NT - 1) asm volatile("s_waitcnt vmcnt(2)" ::: "memory");
        else             asm volatile("s_waitcnt vmcnt(0)" ::: "memory");
        __builtin_amdgcn_s_barrier();

        if (kt < NT - 2) {                         // stage tile kt+2 (async)
            gl_lds16(kg + (size_t)(kt + 2) * 4096, &KV[sbuf][0][w * 512]);
            gl_lds16(vg + (size_t)(kt + 2) * 64,   &KV[sbuf][1][w * 512]);
        }
        const unsigned short* Kt = KV[buf][0];
        const unsigned short* Vt = KV[buf][1];

        f32x4 st[2][4];
        #pragma unroll
        for (int qs = 0; qs < 2; ++qs)
            #pragma unroll
            for (int f = 0; f < 4; ++f) st[qs][f] = (f32x4){0.f, 0.f, 0.f, 0.f};
        __builtin_amdgcn_s_setprio(1);
        #pragma unroll
        for (int kc = 0; kc < 2; ++kc) {
            const int ko = kc ? koff1 : koff0;
            bf16x8 a0 = *(const bf16x8*)(Kt + ko);
            bf16x8 a1 = *(const bf16x8*)(Kt + ko + 1024);
            bf16x8 a2 = *(const bf16x8*)(Kt + ko + 2048);
            bf16x8 a3 = *(const bf16x8*)(Kt + ko + 3072);
            #pragma unroll
            for (int qs = 0; qs < 2; ++qs) {
                st[qs][0] = __builtin_amdgcn_mfma_f32_16x16x32_bf16(a0, bq[qs][kc], st[qs][0], 0, 0, 0);
                st[qs][1] = __builtin_amdgcn_mfma_f32_16x16x32_bf16(a1, bq[qs][kc], st[qs][1], 0, 0, 0);
                st[qs][2] = __builtin_amdgcn_mfma_f32_16x16x32_bf16(a2, bq[qs][kc], st[qs][2], 0, 0, 0);
                st[qs][3] = __builtin_amdgcn_mfma_f32_16x16x32_bf16(a3, bq[qs][kc], st[qs][3], 0, 0, 0);
            }
        }
        __builtin_amdgcn_s_setprio(0);

        bf16x8 bp[2][2];
        #pragma unroll
        for (int qs = 0; qs < 2; ++qs) {
            float e0[4], e1[4], e2[4], e3[4];
            #pragma unroll
            for (int r = 0; r < 4; ++r) {
                e0[r] = EXP2(st[qs][0][r]);
                e1[r] = EXP2(st[qs][1][r]);
                e2[r] = EXP2(st[qs][2][r]);
                e3[r] = EXP2(st[qs][3][r]);
            }
            l_run[qs] += ((e0[0]+e0[1])+(e0[2]+e0[3])) + ((e1[0]+e1[1])+(e1[2]+e1[3]))
                       + ((e2[0]+e2[1])+(e2[2]+e2[3])) + ((e3[0]+e3[1])+(e3[2]+e3[3]));
            unsigned int p0[4] = { cvtpk(e0[0],e0[1]), cvtpk(e0[2],e0[3]),
                                   cvtpk(e1[0],e1[1]), cvtpk(e1[2],e1[3]) };
            unsigned int p1[4] = { cvtpk(e2[0],e2[1]), cvtpk(e2[2],e2[3]),
                                   cvtpk(e3[0],e3[1]), cvtpk(e3[2],e3[3]) };
            bp[qs][0] = *(bf16x8*)p0;
            bp[qs][1] = *(bf16x8*)p1;
        }

        __builtin_amdgcn_s_setprio(1);
        #pragma unroll
        for (int kc = 0; kc < 2; ++kc) {
            const int ko = kc ? koff1 : koff0;
            bf16x8 v0 = *(const bf16x8*)(Vt + ko);
            bf16x8 v1 = *(const bf16x8*)(Vt + ko + 1024);
            bf16x8 v2 = *(const bf16x8*)(Vt + ko + 2048);
            bf16x8 v3 = *(const bf16x8*)(Vt + ko + 3072);
            #pragma unroll
            for (int qs = 0; qs < 2; ++qs) {
                o_acc[qs][0] = __builtin_amdgcn_mfma_f32_16x16x32_bf16(v0, bp[qs][kc], o_acc[qs][0], 0, 0, 0);
                o_acc[qs][1] = __builtin_amdgcn_mfma_f32_16x16x32_bf16(v1, bp[qs][kc], o_acc[qs][1], 0, 0, 0);
                o_acc[qs][2] = __builtin_amdgcn_mfma_f32_16x16x32_bf16(v2, bp[qs][kc], o_acc[qs][2], 0, 0, 0);
                o_acc[qs][3] = __builtin_amdgcn_mfma_f32_16x16x32_bf16(v3, bp[qs][kc], o_acc[qs][3], 0, 0, 0);
            }
        }
        __builtin_amdgcn_s_setprio(0);

        buf  = (buf  == 2) ? 0 : buf  + 1;
        sbuf = (sbuf == 2) ? 0 : sbuf + 1;
    }

    #pragma unroll
    for (int qs = 0; qs < 2; ++qs) {
        l_run[qs] += __shfl_xor(l_run[qs], 16);
        l_run[qs] += __shfl_xor(l_run[qs], 32);
    }

    #pragma unroll
    for (int qs = 0; qs < 2; ++qs) {
        float inv_l = 1.f / l_run[qs];
        unsigned short* op = Ob
            + ((size_t)(b * Sn + q0 + 32*w + 16*qs + qh)) * 512 + h*64 + 4*g;
        #pragma unroll
        for (int f = 0; f < 4; ++f) {
            unsigned int lo = cvtpk(o_acc[qs][f][0] * inv_l, o_acc[qs][f][1] * inv_l);
            unsigned int hi = cvtpk(o_acc[qs][f][2] * inv_l, o_acc[qs][f][3] * inv_l);
            *(uint2*)(op + 16*f) = make_uint2(lo, hi);
        }
    }
}

// ---------------- Kernel 3: MFMA output projection --------------------------
// out[bs][n] = Ob[bs][0:512] @ WOT^T ; A=Ob rows, B=WOT[n][k]. fp32 out.
__global__ __launch_bounds__(256) void out_mfma(
    const unsigned short* __restrict__ Ob, const unsigned short* __restrict__ WOT,
    float* __restrict__ out)
{
    __shared__ __align__(16) unsigned short As[64 * 72];
    __shared__ __align__(16) unsigned short Bs[64 * 72];

    const int t  = threadIdx.x;
    const int w  = t >> 6, ln = t & 63;
    const int qh = ln & 15, g = ln >> 4;
    const int bs0 = blockIdx.x * 64;

    f32x4 acc[4];
    for (int n = 0; n < 4; ++n) acc[n] = (f32x4){0.f, 0.f, 0.f, 0.f};

    for (int k0 = 0; k0 < 512; k0 += 64) {
        __syncthreads();
        for (int i = 0; i < 2; ++i) {
            int idx = i * 256 + t;
            int r = idx >> 3, c = (idx & 7) * 8;
            *(bf16x8*)(As + r*72 + c) =
                *(const bf16x8*)(Ob + ((size_t)(bs0 + r)) * 512 + k0 + c);
            *(bf16x8*)(Bs + r*72 + c) =
                *(const bf16x8*)(WOT + (size_t)r * Dn + k0 + c);
        }
        __syncthreads();
        #pragma unroll
        for (int kc = 0; kc < 2; ++kc) {
            bf16x8 a = *(const bf16x8*)(As + (16*w + qh)*72 + 32*kc + 8*g);
            #pragma unroll
            for (int n = 0; n < 4; ++n) {
                bf16x8 bb = *(const bf16x8*)(Bs + (16*n + qh)*72 + 32*kc + 8*g);
                acc[n] = __builtin_amdgcn_mfma_f32_16x16x32_bf16(a, bb, acc[n], 0, 0, 0);
            }
        }
    }
    // C: col=lane&15 -> n-col = 16nt+qh ; row = 4g+reg -> m = 16w+4g+r
    for (int n = 0; n < 4; ++n)
        for (int r = 0; r < 4; ++r)
            out[((size_t)(bs0 + 16*w + 4*g + r)) * 64 + 16*n + qh] = acc[n][r];
}

extern "C" void kernel_launch(void* const* d_in, const int* in_sizes, int n_in,
                              void* d_out, int out_size, void* d_ws, size_t ws_size,
                              hipStream_t stream)
{
    const float* x  = (const float*)d_in[0];
    const float* WQ = (const float*)d_in[1];
    const float* WK = (const float*)d_in[2];
    const float* WV = (const float*)d_in[3];
    const float* WO = (const float*)d_in[4];
    float* out = (float*)d_out;

    const size_t NQ = (size_t)Bn * Hn * Sn * LATn;     // 8,388,608
    char* p = (char*)d_ws;
    unsigned short* Qb  = (unsigned short*)p;           p += NQ * 2;            // 16MB
    unsigned short* Kb  = (unsigned short*)p;           p += NQ * 2;            // 16MB
    unsigned short* VT  = (unsigned short*)p;           p += NQ * 2;            // 16MB
    unsigned short* WT  = (unsigned short*)p;           p += ((size_t)Hn*192*Dn + 64*Dn) * 2;
    unsigned short* Ob  = (unsigned short*)p;                                   // 16MB
    unsigned short* WOT = WT + (size_t)Hn * 192 * Dn;
    unsigned short* Xb  = Ob;   // alias: Xb dead before flash writes Ob

    xprep     <<<dim3(2048),          256, 0, stream>>>(x, Xb);
    wprep     <<<dim3(8, 25),         256, 0, stream>>>(WQ, WK, WV, WO, WT);
    qkv_mfma  <<<dim3(Sn/64, Bn*Hn),  256, 0, stream>>>(Xb, WT, Qb, Kb, VT);
    flash_mfma<<<dim3(Sn/256, Bn*Hn), 512, 0, stream>>>(Qb, Kb, VT, Ob);
    out_mfma  <<<dim3(Bn*Sn/64),      256, 0, stream>>>(Ob, WOT, out);
}

// Round 9
// 212.400 us; speedup vs baseline: 1.0314x; 1.0314x over previous
//
#include <hip/hip_runtime.h>
#include <hip/hip_bf16.h>
#include <math.h>

// MHA B=8,S=2048,D=512,H=8,LAT=64,OUT=64. fp32 in/out.
// R22: fix R21's qkv vmcnt-FIFO serialization. R21 issued W global->VGPR loads
// AFTER the barrier and consumed them immediately -> the FIFO wait drained the
// async x-staging every K-step (prefetch defeated; qkv ~82us, no better than
// the old sync version). Now W(kt+1) is loaded one K-step ahead (full unroll,
// SSA renames the double set away): consumption is ~2000cy after issue.
// flash (R19) / out / wprep / xprep unchanged; arithmetic bit-identical.
static constexpr int Bn = 8, Sn = 2048, Dn = 512, Hn = 8, LATn = 64, OUTn = 64;

typedef short  bf16x8 __attribute__((ext_vector_type(8)));
typedef float  f32x4  __attribute__((ext_vector_type(4)));

__device__ __forceinline__ unsigned short f2bf(float f) {   // RNE (prep kernels)
    union { float f; unsigned int i; } v; v.f = f;
    unsigned int x = v.i;
    return (unsigned short)((x + 0x7FFFu + ((x >> 16) & 1u)) >> 16);
}
// pack two floats -> two bf16 (round-half-up: bias 2^-17 rel, ~RNE quality)
__device__ __forceinline__ unsigned int pack2bf(float a, float b) {
    unsigned int ua = __float_as_uint(a) + 0x8000u;
    unsigned int ub = __float_as_uint(b) + 0x8000u;
    return (ua >> 16) | (ub & 0xFFFF0000u);
}
// HW packed f32->bf16 (RNE), low16=cvt(a) high16=cvt(b)
__device__ __forceinline__ unsigned int cvtpk(float a, float b) {
    unsigned int r;
    asm("v_cvt_pk_bf16_f32 %0, %1, %2" : "=v"(r) : "v"(a), "v"(b));
    return r;
}

#if __has_builtin(__builtin_amdgcn_exp2f)
#define EXP2(x) __builtin_amdgcn_exp2f(x)
#else
#define EXP2(x) exp2f(x)
#endif

// async 16B global->LDS; vmcnt-tracked; LDS dest = wave-uniform base + lane*16
__device__ __forceinline__ void gl_lds16(const void* g, void* l) {
    __builtin_amdgcn_global_load_lds(
        (const __attribute__((address_space(1))) unsigned int*)g,
        (__attribute__((address_space(3))) unsigned int*)l, 16, 0, 0);
}

// ---------------- Kernel 0a: x fp32 -> bf16 (once; Xb aliases Ob) -----------
__global__ __launch_bounds__(256) void xprep(
    const float* __restrict__ x, unsigned short* __restrict__ Xb)
{
    const size_t base = ((size_t)blockIdx.x * 256 + threadIdx.x) * 16;
    const float* src = x + base;
    float4 u0 = *(const float4*)(src);
    float4 u1 = *(const float4*)(src + 4);
    float4 u2 = *(const float4*)(src + 8);
    float4 u3 = *(const float4*)(src + 12);
    unsigned int pk[8] = { pack2bf(u0.x,u0.y), pack2bf(u0.z,u0.w),
                           pack2bf(u1.x,u1.y), pack2bf(u1.z,u1.w),
                           pack2bf(u2.x,u2.y), pack2bf(u2.z,u2.w),
                           pack2bf(u3.x,u3.y), pack2bf(u3.z,u3.w) };
    *(bf16x8*)(Xb + base)     = *(bf16x8*)(pk);
    *(bf16x8*)(Xb + base + 8) = *(bf16x8*)(pk + 4);
}

// ---------------- Kernel 0b: weight prep ------------------------------------
// WT[h][192][512] bf16 (Q slice scaled by 0.125*log2e), then WOT[64][512].
__global__ __launch_bounds__(256) void wprep(
    const float* __restrict__ WQ, const float* __restrict__ WK,
    const float* __restrict__ WV, const float* __restrict__ WO,
    unsigned short* __restrict__ WT)
{
    __shared__ float tile[64][65];
    const int t  = threadIdx.x;
    const int d0 = blockIdx.x * 64;
    const int yy = blockIdx.y;

    const float* W; float scale = 1.0f; size_t dstbase;
    if (yy < 24) {
        int h = yy / 3, which = yy % 3;
        W = (which == 0) ? WQ : (which == 1) ? WK : WV;
        W += (size_t)h * Dn * 64;
        if (which == 0) scale = 0.125f * 1.44269504088896f;   // fold 1/8 * log2(e)
        dstbase = ((size_t)h * 192 + which * 64) * Dn;
    } else {
        W = WO;                                                // [512][64]
        dstbase = (size_t)8 * 192 * Dn;                        // WOT after QKV
    }

    for (int i = 0; i < 4; ++i) {
        int idx = i * 256 + t;
        int r = idx >> 4, c = (idx & 15) * 4;
        float4 u = *(const float4*)(W + (size_t)(d0 + r) * 64 + c);
        tile[r][c] = u.x; tile[r][c+1] = u.y; tile[r][c+2] = u.z; tile[r][c+3] = u.w;
    }
    __syncthreads();
    const int n = t & 63, dd = t >> 6;
    unsigned short pk[16];
    for (int i = 0; i < 16; ++i) pk[i] = f2bf(tile[dd*16 + i][n] * scale);
    size_t dst = dstbase + (size_t)n * Dn + d0 + dd * 16;
    *(bf16x8*)(WT + dst)     = *(bf16x8*)(pk);
    *(bf16x8*)(WT + dst + 8) = *(bf16x8*)(pk + 8);
}

// ---------------- Kernel 1: MFMA QKV projection (R22: W pipelined) ----------
// Block = (s-tile 64, bh). x-tile from Xb via global_load_lds (dbuf, XOR chunk
// swizzle); W fragments global->VGPR loaded ONE K-STEP AHEAD; one
// vmcnt(0)+barrier per K-step. Values element-identical to R17.
__global__ __launch_bounds__(256, 4) void qkv_mfma(
    const unsigned short* __restrict__ Xb, const unsigned short* __restrict__ WT,
    unsigned short* __restrict__ Qb, unsigned short* __restrict__ Kb,
    unsigned short* __restrict__ VT)
{
    __shared__ __align__(16) unsigned short lds[64 * 200];   // 25.6 KB
    unsigned short* L = lds;                                  // epilogue view
    // staging view: Xs[buf] = lds + 4096*buf (64 rows x 8 chunks x 8 shorts)

    const int t  = threadIdx.x;
    const int w  = t >> 6, ln = t & 63;
    const int nl = ln & 15, g = ln >> 4;
    const int bh = blockIdx.y, b = bh >> 3, h = bh & 7;
    const int s0 = blockIdx.x * 64;

    // x staging: thread t owns chunks t and 256+t of the 512-chunk tile.
    // lds chunk (r,c) holds global chunk (r, c^(r&7))  [verified flash pattern]
    const int r0 = t >> 3,      sc0 = (t & 7) ^ (r0 & 7);
    const int r1 = 32 + (t>>3), sc1 = (t & 7) ^ (r1 & 7);
    const unsigned short* xg0 = Xb + ((size_t)(b * Sn + s0 + r0)) * Dn + sc0 * 8;
    const unsigned short* xg1 = Xb + ((size_t)(b * Sn + s0 + r1)) * Dn + sc1 * 8;

    // A-fragment read offsets (swizzled), row = 16m+nl, chunk (4kc+g)^(nl&7)
    const int p = nl & 7;
    const int aoff0 = nl * 64 + 8 * ((g    ) ^ p);
    const int aoff1 = nl * 64 + 8 * ((4 + g) ^ p);

    // W direct-load lane base: row 48w+16j+nl, cols k0+32kc+8g
    const unsigned short* wb = WT + ((size_t)h * 192 + 48 * w + nl) * Dn + 8 * g;

    f32x4 acc[4][3];
    for (int m = 0; m < 4; ++m)
        for (int j = 0; j < 3; ++j) acc[m][j] = (f32x4){0.f, 0.f, 0.f, 0.f};

    // prologue: stage x k-slice 0 into buf 0 + W fragments for step 0
    gl_lds16(xg0, lds + 512 * w);
    gl_lds16(xg1, lds + 2048 + 512 * w);
    bf16x8 wv[3][2];
    #pragma unroll
    for (int j = 0; j < 3; ++j) {
        wv[j][0] = *(const bf16x8*)(wb + j * 8192);
        wv[j][1] = *(const bf16x8*)(wb + j * 8192 + 32);
    }

    #pragma unroll
    for (int kt = 0; kt < 8; ++kt) {
        asm volatile("s_waitcnt vmcnt(0)" ::: "memory");
        __builtin_amdgcn_s_barrier();
        bf16x8 wn[3][2];                           // next-step W (issued early)
        if (kt < 7) {
            unsigned short* dst = lds + 4096 * ((kt + 1) & 1);
            gl_lds16(xg0 + (kt + 1) * 64, dst + 512 * w);
            gl_lds16(xg1 + (kt + 1) * 64, dst + 2048 + 512 * w);
            #pragma unroll
            for (int j = 0; j < 3; ++j) {
                wn[j][0] = *(const bf16x8*)(wb + j * 8192 + (kt + 1) * 64);
                wn[j][1] = *(const bf16x8*)(wb + j * 8192 + (kt + 1) * 64 + 32);
            }
        }
        const unsigned short* cur = lds + 4096 * (kt & 1);

        #pragma unroll
        for (int kc = 0; kc < 2; ++kc) {
            bf16x8 a[4];
            #pragma unroll
            for (int m = 0; m < 4; ++m)
                a[m] = *(const bf16x8*)(cur + (kc ? aoff1 : aoff0) + m * 1024);
            #pragma unroll
            for (int m = 0; m < 4; ++m)
                #pragma unroll
                for (int j = 0; j < 3; ++j)
                    acc[m][j] = __builtin_amdgcn_mfma_f32_16x16x32_bf16(
                                    a[m], wv[j][kc], acc[m][j], 0, 0, 0);
        }
        if (kt < 7) {                              // rotate (renamed away by unroll)
            #pragma unroll
            for (int j = 0; j < 3; ++j) {
                wv[j][0] = wn[j][0];
                wv[j][1] = wn[j][1];
            }
        }
    }
    __syncthreads();
    for (int m = 0; m < 4; ++m)                    // C: col=lane&15, row=4g+reg
        for (int j = 0; j < 3; ++j) {
            int n = 48*w + 16*j + nl;
            for (int r = 0; r < 4; ++r)
                L[(16*m + 4*g + r)*200 + n] = f2bf(acc[m][j][r]);
        }
    __syncthreads();
    for (int i = 0; i < 4; ++i) {                  // Qb/Kb row-major
        int idx = i * 256 + t;
        int r = idx >> 4, c = (idx & 15) * 8;
        bf16x8 v = *(const bf16x8*)(L + r*200 + c);
        size_t o = ((size_t)bh * Sn + s0 + r) * 64;
        if (c < 64) *(bf16x8*)(Qb + o + c)      = v;
        else        *(bf16x8*)(Kb + o + c - 64) = v;
    }
    {   // VT[bh][o][s], sigma k-permuted within 32-blocks (for in-reg P in flash)
        int o = t & 63, cc = t >> 6;
        unsigned short pk[16];
        for (int i = 0; i < 16; ++i) {
            int srow = 32*(cc>>1) + 16*((i>>2)&1) + 8*(cc&1) + 4*((i>>3)&1) + (i&3);
            pk[i] = L[srow*200 + 128 + o];
        }
        size_t dst = ((size_t)bh * 64 + o) * Sn + s0 + 16*cc;
        *(bf16x8*)(VT + dst)     = *(bf16x8*)(pk);
        *(bf16x8*)(VT + dst + 8) = *(bf16x8*)(pk + 8);
    }
}

// ---------------- Kernel 2: MFMA flash attention (R19, unchanged) -----------
// 8 waves x 32 q-rows (2 q-sets), 256 q/block, grid (8,64)=2 blocks/CU.
// In-register P (sigma-permuted V). 3-buffer KV, depth-2 prefetch,
// one s_barrier/tile, vmcnt(2) counted. setprio on MFMA.
__global__ __launch_bounds__(512, 4) void flash_mfma(
    const unsigned short* __restrict__ Qb,
    const unsigned short* __restrict__ Kb,
    const unsigned short* __restrict__ VT,
    unsigned short* __restrict__ Ob)
{
    __shared__ __align__(16) unsigned short KV[3][2][4096];   // 48 KB

    const int t  = threadIdx.x;                    // 512 threads, 8 waves
    const int w  = t >> 6, ln = t & 63;
    const int qh = ln & 15, g = (ln >> 4) & 3;
    const int bh = blockIdx.y, b = bh >> 3, h = bh & 7;
    const int q0 = blockIdx.x * 256;
    const int qw = q0 + 32 * w;                    // this wave's 32 q rows

    bf16x8 bq[2][2];
    #pragma unroll
    for (int qs = 0; qs < 2; ++qs) {
        const unsigned short* qp =
            Qb + ((size_t)bh * Sn + qw + 16*qs + qh) * 64 + 8*g;
        bq[qs][0] = *(const bf16x8*)(qp);
        bq[qs][1] = *(const bf16x8*)(qp + 32);
    }

    const int r0 = t >> 3;                         // tile row 0..63
    const int cs = (t & 7) ^ (r0 & 7);             // swizzled source chunk col
    const unsigned short* kg = Kb + ((size_t)bh * Sn + r0) * 64 + cs * 8;
    const unsigned short* vg = VT + ((size_t)bh * 64 + r0) * Sn + cs * 8;

    const int koff0 = qh*64 + (((g    ) ^ (qh & 7)) * 8);
    const int koff1 = qh*64 + (((4 + g) ^ (qh & 7)) * 8);

    f32x4 o_acc[2][4];
    #pragma unroll
    for (int qs = 0; qs < 2; ++qs)
        #pragma unroll
        for (int f = 0; f < 4; ++f) o_acc[qs][f] = (f32x4){0.f, 0.f, 0.f, 0.f};
    float l_run[2] = {0.f, 0.f};

    gl_lds16(kg,        &KV[0][0][w * 512]);
    gl_lds16(vg,        &KV[0][1][w * 512]);
    gl_lds16(kg + 4096, &KV[1][0][w * 512]);
    gl_lds16(vg + 64,   &KV[1][1][w * 512]);

    constexpr int NT = Sn / 64;                    // 32 tiles
    int buf = 0, sbuf = 2;
    for (int kt = 0; kt < NT; ++kt) {
        if (kt < NT - 1) asm volatile("s_waitcnt vmcnt(2)" ::: "memory");
        else             asm volatile("s_waitcnt vmcnt(0)" ::: "memory");
        __builtin_amdgcn_s_barrier();

        if (kt < NT - 2) {                         // stage tile kt+2 (async)
            gl_lds16(kg + (size_t)(kt + 2) * 4096, &KV[sbuf][0][w * 512]);
            gl_lds16(vg + (size_t)(kt + 2) * 64,   &KV[sbuf][1][w * 512]);
        }
        const unsigned short* Kt = KV[buf][0];
        const unsigned short* Vt = KV[buf][1];

        f32x4 st[2][4];
        #pragma unroll
        for (int qs = 0; qs < 2; ++qs)
            #pragma unroll
            for (int f = 0; f < 4; ++f) st[qs][f] = (f32x4){0.f, 0.f, 0.f, 0.f};
        __builtin_amdgcn_s_setprio(1);
        #pragma unroll
        for (int kc = 0; kc < 2; ++kc) {
            const int ko = kc ? koff1 : koff0;
            bf16x8 a0 = *(const bf16x8*)(Kt + ko);
            bf16x8 a1 = *(const bf16x8*)(Kt + ko + 1024);
            bf16x8 a2 = *(const bf16x8*)(Kt + ko + 2048);
            bf16x8 a3 = *(const bf16x8*)(Kt + ko + 3072);
            #pragma unroll
            for (int qs = 0; qs < 2; ++qs) {
                st[qs][0] = __builtin_amdgcn_mfma_f32_16x16x32_bf16(a0, bq[qs][kc], st[qs][0], 0, 0, 0);
                st[qs][1] = __builtin_amdgcn_mfma_f32_16x16x32_bf16(a1, bq[qs][kc], st[qs][1], 0, 0, 0);
                st[qs][2] = __builtin_amdgcn_mfma_f32_16x16x32_bf16(a2, bq[qs][kc], st[qs][2], 0, 0, 0);
                st[qs][3] = __builtin_amdgcn_mfma_f32_16x16x32_bf16(a3, bq[qs][kc], st[qs][3], 0, 0, 0);
            }
        }
        __builtin_amdgcn_s_setprio(0);

        bf16x8 bp[2][2];
        #pragma unroll
        for (int qs = 0; qs < 2; ++qs) {
            float e0[4], e1[4], e2[4], e3[4];
            #pragma unroll
            for (int r = 0; r < 4; ++r) {
                e0[r] = EXP2(st[qs][0][r]);
                e1[r] = EXP2(st[qs][1][r]);
                e2[r] = EXP2(st[qs][2][r]);
                e3[r] = EXP2(st[qs][3][r]);
            }
            l_run[qs] += ((e0[0]+e0[1])+(e0[2]+e0[3])) + ((e1[0]+e1[1])+(e1[2]+e1[3]))
                       + ((e2[0]+e2[1])+(e2[2]+e2[3])) + ((e3[0]+e3[1])+(e3[2]+e3[3]));
            unsigned int p0[4] = { cvtpk(e0[0],e0[1]), cvtpk(e0[2],e0[3]),
                                   cvtpk(e1[0],e1[1]), cvtpk(e1[2],e1[3]) };
            unsigned int p1[4] = { cvtpk(e2[0],e2[1]), cvtpk(e2[2],e2[3]),
                                   cvtpk(e3[0],e3[1]), cvtpk(e3[2],e3[3]) };
            bp[qs][0] = *(bf16x8*)p0;
            bp[qs][1] = *(bf16x8*)p1;
        }

        __builtin_amdgcn_s_setprio(1);
        #pragma unroll
        for (int kc = 0; kc < 2; ++kc) {
            const int ko = kc ? koff1 : koff0;
            bf16x8 v0 = *(const bf16x8*)(Vt + ko);
            bf16x8 v1 = *(const bf16x8*)(Vt + ko + 1024);
            bf16x8 v2 = *(const bf16x8*)(Vt + ko + 2048);
            bf16x8 v3 = *(const bf16x8*)(Vt + ko + 3072);
            #pragma unroll
            for (int qs = 0; qs < 2; ++qs) {
                o_acc[qs][0] = __builtin_amdgcn_mfma_f32_16x16x32_bf16(v0, bp[qs][kc], o_acc[qs][0], 0, 0, 0);
                o_acc[qs][1] = __builtin_amdgcn_mfma_f32_16x16x32_bf16(v1, bp[qs][kc], o_acc[qs][1], 0, 0, 0);
                o_acc[qs][2] = __builtin_amdgcn_mfma_f32_16x16x32_bf16(v2, bp[qs][kc], o_acc[qs][2], 0, 0, 0);
                o_acc[qs][3] = __builtin_amdgcn_mfma_f32_16x16x32_bf16(v3, bp[qs][kc], o_acc[qs][3], 0, 0, 0);
            }
        }
        __builtin_amdgcn_s_setprio(0);

        buf  = (buf  == 2) ? 0 : buf  + 1;
        sbuf = (sbuf == 2) ? 0 : sbuf + 1;
    }

    #pragma unroll
    for (int qs = 0; qs < 2; ++qs) {
        l_run[qs] += __shfl_xor(l_run[qs], 16);
        l_run[qs] += __shfl_xor(l_run[qs], 32);
    }

    #pragma unroll
    for (int qs = 0; qs < 2; ++qs) {
        float inv_l = 1.f / l_run[qs];
        unsigned short* op = Ob
            + ((size_t)(b * Sn + q0 + 32*w + 16*qs + qh)) * 512 + h*64 + 4*g;
        #pragma unroll
        for (int f = 0; f < 4; ++f) {
            unsigned int lo = cvtpk(o_acc[qs][f][0] * inv_l, o_acc[qs][f][1] * inv_l);
            unsigned int hi = cvtpk(o_acc[qs][f][2] * inv_l, o_acc[qs][f][3] * inv_l);
            *(uint2*)(op + 16*f) = make_uint2(lo, hi);
        }
    }
}

// ---------------- Kernel 3: MFMA output projection --------------------------
// out[bs][n] = Ob[bs][0:512] @ WOT^T ; A=Ob rows, B=WOT[n][k]. fp32 out.
__global__ __launch_bounds__(256) void out_mfma(
    const unsigned short* __restrict__ Ob, const unsigned short* __restrict__ WOT,
    float* __restrict__ out)
{
    __shared__ __align__(16) unsigned short As[64 * 72];
    __shared__ __align__(16) unsigned short Bs[64 * 72];

    const int t  = threadIdx.x;
    const int w  = t >> 6, ln = t & 63;
    const int qh = ln & 15, g = ln >> 4;
    const int bs0 = blockIdx.x * 64;

    f32x4 acc[4];
    for (int n = 0; n < 4; ++n) acc[n] = (f32x4){0.f, 0.f, 0.f, 0.f};

    for (int k0 = 0; k0 < 512; k0 += 64) {
        __syncthreads();
        for (int i = 0; i < 2; ++i) {
            int idx = i * 256 + t;
            int r = idx >> 3, c = (idx & 7) * 8;
            *(bf16x8*)(As + r*72 + c) =
                *(const bf16x8*)(Ob + ((size_t)(bs0 + r)) * 512 + k0 + c);
            *(bf16x8*)(Bs + r*72 + c) =
                *(const bf16x8*)(WOT + (size_t)r * Dn + k0 + c);
        }
        __syncthreads();
        #pragma unroll
        for (int kc = 0; kc < 2; ++kc) {
            bf16x8 a = *(const bf16x8*)(As + (16*w + qh)*72 + 32*kc + 8*g);
            #pragma unroll
            for (int n = 0; n < 4; ++n) {
                bf16x8 bb = *(const bf16x8*)(Bs + (16*n + qh)*72 + 32*kc + 8*g);
                acc[n] = __builtin_amdgcn_mfma_f32_16x16x32_bf16(a, bb, acc[n], 0, 0, 0);
            }
        }
    }
    // C: col=lane&15 -> n-col = 16nt+qh ; row = 4g+reg -> m = 16w+4g+r
    for (int n = 0; n < 4; ++n)
        for (int r = 0; r < 4; ++r)
            out[((size_t)(bs0 + 16*w + 4*g + r)) * 64 + 16*n + qh] = acc[n][r];
}

extern "C" void kernel_launch(void* const* d_in, const int* in_sizes, int n_in,
                              void* d_out, int out_size, void* d_ws, size_t ws_size,
                              hipStream_t stream)
{
    const float* x  = (const float*)d_in[0];
    const float* WQ = (const float*)d_in[1];
    const float* WK = (const float*)d_in[2];
    const float* WV = (const float*)d_in[3];
    const float* WO = (const float*)d_in[4];
    float* out = (float*)d_out;

    const size_t NQ = (size_t)Bn * Hn * Sn * LATn;     // 8,388,608
    char* p = (char*)d_ws;
    unsigned short* Qb  = (unsigned short*)p;           p += NQ * 2;            // 16MB
    unsigned short* Kb  = (unsigned short*)p;           p += NQ * 2;            // 16MB
    unsigned short* VT  = (unsigned short*)p;           p += NQ * 2;            // 16MB
    unsigned short* WT  = (unsigned short*)p;           p += ((size_t)Hn*192*Dn + 64*Dn) * 2;
    unsigned short* Ob  = (unsigned short*)p;                                   // 16MB
    unsigned short* WOT = WT + (size_t)Hn * 192 * Dn;
    unsigned short* Xb  = Ob;   // alias: Xb dead before flash writes Ob

    xprep     <<<dim3(2048),          256, 0, stream>>>(x, Xb);
    wprep     <<<dim3(8, 25),         256, 0, stream>>>(WQ, WK, WV, WO, WT);
    qkv_mfma  <<<dim3(Sn/64, Bn*Hn),  256, 0, stream>>>(Xb, WT, Qb, Kb, VT);
    flash_mfma<<<dim3(Sn/256, Bn*Hn), 512, 0, stream>>>(Qb, Kb, VT, Ob);
    out_mfma  <<<dim3(Bn*Sn/64),      256, 0, stream>>>(Ob, WOT, out);
}

// Round 10
// 212.042 us; speedup vs baseline: 1.0332x; 1.0017x over previous
//
#include <hip/hip_runtime.h>
#include <hip/hip_bf16.h>
#include <math.h>

// MHA B=8,S=2048,D=512,H=8,LAT=64,OUT=64. fp32 in/out.
// R23: qkv spill fix + XCD locality + async out.
//  - qkv launch_bounds (256,3): R22's (256,4) capped VGPR at 128 < ~134 needed
//    (acc48+wv24+wn24+frags+addr) -> inner-loop scratch spills. 170 cap fixes.
//  - qkv XCD-bijective grid swizzle: logical=(id&7)*256+(id>>3) -> XCD c owns
//    batch c; 2MB x panels + 1.5MB WT stay L2-resident; x HBM 128MB -> ~16MB.
//  - out_mfma rebuilt as clone of flash's verified async loop (gl_lds16, XOR
//    chunk swizzle, 3-buf, depth-2 prefetch, counted vmcnt(4), 1 barrier/step).
//  - xprep+wprep fused into one `prep` kernel (one less launch gap).
// flash (R19) unchanged; all arithmetic element-identical -> absmax 0.005859375.
static constexpr int Bn = 8, Sn = 2048, Dn = 512, Hn = 8, LATn = 64, OUTn = 64;

typedef short  bf16x8 __attribute__((ext_vector_type(8)));
typedef float  f32x4  __attribute__((ext_vector_type(4)));

__device__ __forceinline__ unsigned short f2bf(float f) {   // RNE (prep kernels)
    union { float f; unsigned int i; } v; v.f = f;
    unsigned int x = v.i;
    return (unsigned short)((x + 0x7FFFu + ((x >> 16) & 1u)) >> 16);
}
// pack two floats -> two bf16 (round-half-up: bias 2^-17 rel, ~RNE quality)
__device__ __forceinline__ unsigned int pack2bf(float a, float b) {
    unsigned int ua = __float_as_uint(a) + 0x8000u;
    unsigned int ub = __float_as_uint(b) + 0x8000u;
    return (ua >> 16) | (ub & 0xFFFF0000u);
}
// HW packed f32->bf16 (RNE), low16=cvt(a) high16=cvt(b)
__device__ __forceinline__ unsigned int cvtpk(float a, float b) {
    unsigned int r;
    asm("v_cvt_pk_bf16_f32 %0, %1, %2" : "=v"(r) : "v"(a), "v"(b));
    return r;
}

#if __has_builtin(__builtin_amdgcn_exp2f)
#define EXP2(x) __builtin_amdgcn_exp2f(x)
#else
#define EXP2(x) exp2f(x)
#endif

// async 16B global->LDS; vmcnt-tracked; LDS dest = wave-uniform base + lane*16
__device__ __forceinline__ void gl_lds16(const void* g, void* l) {
    __builtin_amdgcn_global_load_lds(
        (const __attribute__((address_space(1))) unsigned int*)g,
        (__attribute__((address_space(3))) unsigned int*)l, 16, 0, 0);
}

// ---------------- Kernel 0: fused prep (xprep blocks 0..2047, wprep 2048+) --
// Xb = x as bf16 (Xb aliases Ob). WT[h][192][512] bf16 (Q slice scaled by
// 0.125*log2e), then WOT[64][512].
__global__ __launch_bounds__(256) void prep(
    const float* __restrict__ x,
    const float* __restrict__ WQ, const float* __restrict__ WK,
    const float* __restrict__ WV, const float* __restrict__ WO,
    unsigned short* __restrict__ Xb, unsigned short* __restrict__ WT)
{
    __shared__ float tile[64][65];
    const int id = blockIdx.x;
    const int t  = threadIdx.x;

    if (id < 2048) {                               // ---- xprep path ----
        const size_t base = ((size_t)id * 256 + t) * 16;
        const float* src = x + base;
        float4 u0 = *(const float4*)(src);
        float4 u1 = *(const float4*)(src + 4);
        float4 u2 = *(const float4*)(src + 8);
        float4 u3 = *(const float4*)(src + 12);
        unsigned int pk[8] = { pack2bf(u0.x,u0.y), pack2bf(u0.z,u0.w),
                               pack2bf(u1.x,u1.y), pack2bf(u1.z,u1.w),
                               pack2bf(u2.x,u2.y), pack2bf(u2.z,u2.w),
                               pack2bf(u3.x,u3.y), pack2bf(u3.z,u3.w) };
        *(bf16x8*)(Xb + base)     = *(bf16x8*)(pk);
        *(bf16x8*)(Xb + base + 8) = *(bf16x8*)(pk + 4);
        return;
    }

    // ---- wprep path ----
    const int rem = id - 2048;                     // 0..199
    const int d0 = (rem & 7) * 64;
    const int yy = rem >> 3;                       // 0..24

    const float* W; float scale = 1.0f; size_t dstbase;
    if (yy < 24) {
        int h = yy / 3, which = yy % 3;
        W = (which == 0) ? WQ : (which == 1) ? WK : WV;
        W += (size_t)h * Dn * 64;
        if (which == 0) scale = 0.125f * 1.44269504088896f;   // fold 1/8 * log2(e)
        dstbase = ((size_t)h * 192 + which * 64) * Dn;
    } else {
        W = WO;                                                // [512][64]
        dstbase = (size_t)8 * 192 * Dn;                        // WOT after QKV
    }

    for (int i = 0; i < 4; ++i) {
        int idx = i * 256 + t;
        int r = idx >> 4, c = (idx & 15) * 4;
        float4 u = *(const float4*)(W + (size_t)(d0 + r) * 64 + c);
        tile[r][c] = u.x; tile[r][c+1] = u.y; tile[r][c+2] = u.z; tile[r][c+3] = u.w;
    }
    __syncthreads();
    const int n = t & 63, dd = t >> 6;
    unsigned short pk[16];
    for (int i = 0; i < 16; ++i) pk[i] = f2bf(tile[dd*16 + i][n] * scale);
    size_t dst = dstbase + (size_t)n * Dn + d0 + dd * 16;
    *(bf16x8*)(WT + dst)     = *(bf16x8*)(pk);
    *(bf16x8*)(WT + dst + 8) = *(bf16x8*)(pk + 8);
}

// ---------------- Kernel 1: MFMA QKV projection (R23) -----------------------
// 1D grid 2048, XCD-bijective swizzle (XCD c owns batch c -> L2-hot x panels).
// x-tile from Xb via global_load_lds (dbuf, XOR chunk swizzle); W fragments
// global->VGPR pipelined one K-step ahead; launch_bounds (256,3) = no spill.
__global__ __launch_bounds__(256, 3) void qkv_mfma(
    const unsigned short* __restrict__ Xb, const unsigned short* __restrict__ WT,
    unsigned short* __restrict__ Qb, unsigned short* __restrict__ Kb,
    unsigned short* __restrict__ VT)
{
    __shared__ __align__(16) unsigned short lds[64 * 200];   // 25.6 KB
    unsigned short* L = lds;                                  // epilogue view

    const int t  = threadIdx.x;
    const int w  = t >> 6, ln = t & 63;
    const int nl = ln & 15, g = ln >> 4;
    // XCD-bijective swizzle: hw id i -> XCD i&7; give XCD c logical chunk
    // [c*256, c*256+256) = batch c's 32 s-tiles x 8 heads.
    const int logical = (blockIdx.x & 7) * 256 + (blockIdx.x >> 3);
    const int s0 = (logical & 31) * 64;
    const int bh = logical >> 5, b = bh >> 3, h = bh & 7;

    // x staging: thread t owns chunks t and 256+t of the 512-chunk tile.
    // lds chunk (r,c) holds global chunk (r, c^(r&7))  [verified flash pattern]
    const int r0 = t >> 3,      sc0 = (t & 7) ^ (r0 & 7);
    const int r1 = 32 + (t>>3), sc1 = (t & 7) ^ (r1 & 7);
    const unsigned short* xg0 = Xb + ((size_t)(b * Sn + s0 + r0)) * Dn + sc0 * 8;
    const unsigned short* xg1 = Xb + ((size_t)(b * Sn + s0 + r1)) * Dn + sc1 * 8;

    // A-fragment read offsets (swizzled), row = 16m+nl, chunk (4kc+g)^(nl&7)
    const int p = nl & 7;
    const int aoff0 = nl * 64 + 8 * ((g    ) ^ p);
    const int aoff1 = nl * 64 + 8 * ((4 + g) ^ p);

    // W direct-load lane base: row 48w+16j+nl, cols k0+32kc+8g
    const unsigned short* wb = WT + ((size_t)h * 192 + 48 * w + nl) * Dn + 8 * g;

    f32x4 acc[4][3];
    for (int m = 0; m < 4; ++m)
        for (int j = 0; j < 3; ++j) acc[m][j] = (f32x4){0.f, 0.f, 0.f, 0.f};

    // prologue: stage x k-slice 0 into buf 0 + W fragments for step 0
    gl_lds16(xg0, lds + 512 * w);
    gl_lds16(xg1, lds + 2048 + 512 * w);
    bf16x8 wv[3][2];
    #pragma unroll
    for (int j = 0; j < 3; ++j) {
        wv[j][0] = *(const bf16x8*)(wb + j * 8192);
        wv[j][1] = *(const bf16x8*)(wb + j * 8192 + 32);
    }

    #pragma unroll
    for (int kt = 0; kt < 8; ++kt) {
        asm volatile("s_waitcnt vmcnt(0)" ::: "memory");
        __builtin_amdgcn_s_barrier();
        bf16x8 wn[3][2];                           // next-step W (issued early)
        if (kt < 7) {
            unsigned short* dst = lds + 4096 * ((kt + 1) & 1);
            gl_lds16(xg0 + (kt + 1) * 64, dst + 512 * w);
            gl_lds16(xg1 + (kt + 1) * 64, dst + 2048 + 512 * w);
            #pragma unroll
            for (int j = 0; j < 3; ++j) {
                wn[j][0] = *(const bf16x8*)(wb + j * 8192 + (kt + 1) * 64);
                wn[j][1] = *(const bf16x8*)(wb + j * 8192 + (kt + 1) * 64 + 32);
            }
        }
        const unsigned short* cur = lds + 4096 * (kt & 1);

        #pragma unroll
        for (int kc = 0; kc < 2; ++kc) {
            bf16x8 a[4];
            #pragma unroll
            for (int m = 0; m < 4; ++m)
                a[m] = *(const bf16x8*)(cur + (kc ? aoff1 : aoff0) + m * 1024);
            #pragma unroll
            for (int m = 0; m < 4; ++m)
                #pragma unroll
                for (int j = 0; j < 3; ++j)
                    acc[m][j] = __builtin_amdgcn_mfma_f32_16x16x32_bf16(
                                    a[m], wv[j][kc], acc[m][j], 0, 0, 0);
        }
        if (kt < 7) {                              // rotate (renamed by unroll)
            #pragma unroll
            for (int j = 0; j < 3; ++j) {
                wv[j][0] = wn[j][0];
                wv[j][1] = wn[j][1];
            }
        }
    }
    __syncthreads();
    for (int m = 0; m < 4; ++m)                    // C: col=lane&15, row=4g+reg
        for (int j = 0; j < 3; ++j) {
            int n = 48*w + 16*j + nl;
            for (int r = 0; r < 4; ++r)
                L[(16*m + 4*g + r)*200 + n] = f2bf(acc[m][j][r]);
        }
    __syncthreads();
    for (int i = 0; i < 4; ++i) {                  // Qb/Kb row-major
        int idx = i * 256 + t;
        int r = idx >> 4, c = (idx & 15) * 8;
        bf16x8 v = *(const bf16x8*)(L + r*200 + c);
        size_t o = ((size_t)bh * Sn + s0 + r) * 64;
        if (c < 64) *(bf16x8*)(Qb + o + c)      = v;
        else        *(bf16x8*)(Kb + o + c - 64) = v;
    }
    {   // VT[bh][o][s], sigma k-permuted within 32-blocks (for in-reg P in flash)
        int o = t & 63, cc = t >> 6;
        unsigned short pk[16];
        for (int i = 0; i < 16; ++i) {
            int srow = 32*(cc>>1) + 16*((i>>2)&1) + 8*(cc&1) + 4*((i>>3)&1) + (i&3);
            pk[i] = L[srow*200 + 128 + o];
        }
        size_t dst = ((size_t)bh * 64 + o) * Sn + s0 + 16*cc;
        *(bf16x8*)(VT + dst)     = *(bf16x8*)(pk);
        *(bf16x8*)(VT + dst + 8) = *(bf16x8*)(pk + 8);
    }
}

// ---------------- Kernel 2: MFMA flash attention (R19, unchanged) -----------
// 8 waves x 32 q-rows (2 q-sets), 256 q/block, grid (8,64)=2 blocks/CU.
// In-register P (sigma-permuted V). 3-buffer KV, depth-2 prefetch,
// one s_barrier/tile, vmcnt(2) counted. setprio on MFMA.
__global__ __launch_bounds__(512, 4) void flash_mfma(
    const unsigned short* __restrict__ Qb,
    const unsigned short* __restrict__ Kb,
    const unsigned short* __restrict__ VT,
    unsigned short* __restrict__ Ob)
{
    __shared__ __align__(16) unsigned short KV[3][2][4096];   // 48 KB

    const int t  = threadIdx.x;                    // 512 threads, 8 waves
    const int w  = t >> 6, ln = t & 63;
    const int qh = ln & 15, g = (ln >> 4) & 3;
    const int bh = blockIdx.y, b = bh >> 3, h = bh & 7;
    const int q0 = blockIdx.x * 256;
    const int qw = q0 + 32 * w;                    // this wave's 32 q rows

    bf16x8 bq[2][2];
    #pragma unroll
    for (int qs = 0; qs < 2; ++qs) {
        const unsigned short* qp =
            Qb + ((size_t)bh * Sn + qw + 16*qs + qh) * 64 + 8*g;
        bq[qs][0] = *(const bf16x8*)(qp);
        bq[qs][1] = *(const bf16x8*)(qp + 32);
    }

    const int r0 = t >> 3;                         // tile row 0..63
    const int cs = (t & 7) ^ (r0 & 7);             // swizzled source chunk col
    const unsigned short* kg = Kb + ((size_t)bh * Sn + r0) * 64 + cs * 8;
    const unsigned short* vg = VT + ((size_t)bh * 64 + r0) * Sn + cs * 8;

    const int koff0 = qh*64 + (((g    ) ^ (qh & 7)) * 8);
    const int koff1 = qh*64 + (((4 + g) ^ (qh & 7)) * 8);

    f32x4 o_acc[2][4];
    #pragma unroll
    for (int qs = 0; qs < 2; ++qs)
        #pragma unroll
        for (int f = 0; f < 4; ++f) o_acc[qs][f] = (f32x4){0.f, 0.f, 0.f, 0.f};
    float l_run[2] = {0.f, 0.f};

    gl_lds16(kg,        &KV[0][0][w * 512]);
    gl_lds16(vg,        &KV[0][1][w * 512]);
    gl_lds16(kg + 4096, &KV[1][0][w * 512]);
    gl_lds16(vg + 64,   &KV[1][1][w * 512]);

    constexpr int NT = Sn / 64;                    // 32 tiles
    int buf = 0, sbuf = 2;
    for (int kt = 0; kt < NT; ++kt) {
        if (kt < NT - 1) asm volatile("s_waitcnt vmcnt(2)" ::: "memory");
        else             asm volatile("s_waitcnt vmcnt(0)" ::: "memory");
        __builtin_amdgcn_s_barrier();

        if (kt < NT - 2) {                         // stage tile kt+2 (async)
            gl_lds16(kg + (size_t)(kt + 2) * 4096, &KV[sbuf][0][w * 512]);
            gl_lds16(vg + (size_t)(kt + 2) * 64,   &KV[sbuf][1][w * 512]);
        }
        const unsigned short* Kt = KV[buf][0];
        const unsigned short* Vt = KV[buf][1];

        f32x4 st[2][4];
        #pragma unroll
        for (int qs = 0; qs < 2; ++qs)
            #pragma unroll
            for (int f = 0; f < 4; ++f) st[qs][f] = (f32x4){0.f, 0.f, 0.f, 0.f};
        __builtin_amdgcn_s_setprio(1);
        #pragma unroll
        for (int kc = 0; kc < 2; ++kc) {
            const int ko = kc ? koff1 : koff0;
            bf16x8 a0 = *(const bf16x8*)(Kt + ko);
            bf16x8 a1 = *(const bf16x8*)(Kt + ko + 1024);
            bf16x8 a2 = *(const bf16x8*)(Kt + ko + 2048);
            bf16x8 a3 = *(const bf16x8*)(Kt + ko + 3072);
            #pragma unroll
            for (int qs = 0; qs < 2; ++qs) {
                st[qs][0] = __builtin_amdgcn_mfma_f32_16x16x32_bf16(a0, bq[qs][kc], st[qs][0], 0, 0, 0);
                st[qs][1] = __builtin_amdgcn_mfma_f32_16x16x32_bf16(a1, bq[qs][kc], st[qs][1], 0, 0, 0);
                st[qs][2] = __builtin_amdgcn_mfma_f32_16x16x32_bf16(a2, bq[qs][kc], st[qs][2], 0, 0, 0);
                st[qs][3] = __builtin_amdgcn_mfma_f32_16x16x32_bf16(a3, bq[qs][kc], st[qs][3], 0, 0, 0);
            }
        }
        __builtin_amdgcn_s_setprio(0);

        bf16x8 bp[2][2];
        #pragma unroll
        for (int qs = 0; qs < 2; ++qs) {
            float e0[4], e1[4], e2[4], e3[4];
            #pragma unroll
            for (int r = 0; r < 4; ++r) {
                e0[r] = EXP2(st[qs][0][r]);
                e1[r] = EXP2(st[qs][1][r]);
                e2[r] = EXP2(st[qs][2][r]);
                e3[r] = EXP2(st[qs][3][r]);
            }
            l_run[qs] += ((e0[0]+e0[1])+(e0[2]+e0[3])) + ((e1[0]+e1[1])+(e1[2]+e1[3]))
                       + ((e2[0]+e2[1])+(e2[2]+e2[3])) + ((e3[0]+e3[1])+(e3[2]+e3[3]));
            unsigned int p0[4] = { cvtpk(e0[0],e0[1]), cvtpk(e0[2],e0[3]),
                                   cvtpk(e1[0],e1[1]), cvtpk(e1[2],e1[3]) };
            unsigned int p1[4] = { cvtpk(e2[0],e2[1]), cvtpk(e2[2],e2[3]),
                                   cvtpk(e3[0],e3[1]), cvtpk(e3[2],e3[3]) };
            bp[qs][0] = *(bf16x8*)p0;
            bp[qs][1] = *(bf16x8*)p1;
        }

        __builtin_amdgcn_s_setprio(1);
        #pragma unroll
        for (int kc = 0; kc < 2; ++kc) {
            const int ko = kc ? koff1 : koff0;
            bf16x8 v0 = *(const bf16x8*)(Vt + ko);
            bf16x8 v1 = *(const bf16x8*)(Vt + ko + 1024);
            bf16x8 v2 = *(const bf16x8*)(Vt + ko + 2048);
            bf16x8 v3 = *(const bf16x8*)(Vt + ko + 3072);
            #pragma unroll
            for (int qs = 0; qs < 2; ++qs) {
                o_acc[qs][0] = __builtin_amdgcn_mfma_f32_16x16x32_bf16(v0, bp[qs][kc], o_acc[qs][0], 0, 0, 0);
                o_acc[qs][1] = __builtin_amdgcn_mfma_f32_16x16x32_bf16(v1, bp[qs][kc], o_acc[qs][1], 0, 0, 0);
                o_acc[qs][2] = __builtin_amdgcn_mfma_f32_16x16x32_bf16(v2, bp[qs][kc], o_acc[qs][2], 0, 0, 0);
                o_acc[qs][3] = __builtin_amdgcn_mfma_f32_16x16x32_bf16(v3, bp[qs][kc], o_acc[qs][3], 0, 0, 0);
            }
        }
        __builtin_amdgcn_s_setprio(0);

        buf  = (buf  == 2) ? 0 : buf  + 1;
        sbuf = (sbuf == 2) ? 0 : sbuf + 1;
    }

    #pragma unroll
    for (int qs = 0; qs < 2; ++qs) {
        l_run[qs] += __shfl_xor(l_run[qs], 16);
        l_run[qs] += __shfl_xor(l_run[qs], 32);
    }

    #pragma unroll
    for (int qs = 0; qs < 2; ++qs) {
        float inv_l = 1.f / l_run[qs];
        unsigned short* op = Ob
            + ((size_t)(b * Sn + q0 + 32*w + 16*qs + qh)) * 512 + h*64 + 4*g;
        #pragma unroll
        for (int f = 0; f < 4; ++f) {
            unsigned int lo = cvtpk(o_acc[qs][f][0] * inv_l, o_acc[qs][f][1] * inv_l);
            unsigned int hi = cvtpk(o_acc[qs][f][2] * inv_l, o_acc[qs][f][3] * inv_l);
            *(uint2*)(op + 16*f) = make_uint2(lo, hi);
        }
    }
}

// ---------------- Kernel 3: MFMA output projection (R23 async rebuild) ------
// Clone of flash's loop: 3-buf, depth-2 prefetch, counted vmcnt(4), XOR chunk
// swizzle, gl_lds16. Fragment VALUES identical to the old verified out_mfma.
__global__ __launch_bounds__(256) void out_mfma(
    const unsigned short* __restrict__ Ob, const unsigned short* __restrict__ WOT,
    float* __restrict__ out)
{
    __shared__ __align__(16) unsigned short AB[3][2][4096];   // 48 KB

    const int t  = threadIdx.x;                    // 256 threads, 4 waves
    const int w  = t >> 6, ln = t & 63;
    const int qh = ln & 15, g = ln >> 4;
    const int bs0 = blockIdx.x * 64;

    // staging: thread t owns chunks t and 256+t of each 512-chunk (64x64) tile.
    // lds chunk (r,c) holds global chunk (r, c^(r&7)).
    const int r0 = t >> 3,      cs0 = (t & 7) ^ (r0 & 7);
    const int r1 = 32 + (t>>3), cs1 = (t & 7) ^ (r1 & 7);
    const unsigned short* ag0 = Ob + ((size_t)(bs0 + r0)) * 512 + cs0 * 8;
    const unsigned short* ag1 = Ob + ((size_t)(bs0 + r1)) * 512 + cs1 * 8;
    const unsigned short* bg0 = WOT + (size_t)r0 * Dn + cs0 * 8;
    const unsigned short* bg1 = WOT + (size_t)r1 * Dn + cs1 * 8;

    // fragment read offsets: A row = 16w+qh, B row = 16n+qh; chunk (4kc+g)^(qh&7)
    const int foff0 = qh*64 + 8 * (((    g) ^ (qh & 7)));
    const int foff1 = qh*64 + 8 * (((4 + g) ^ (qh & 7)));

    f32x4 acc[4];
    for (int n = 0; n < 4; ++n) acc[n] = (f32x4){0.f, 0.f, 0.f, 0.f};

    // prologue: stage k-steps 0,1
    gl_lds16(ag0,      &AB[0][0][w * 512]);        // wave w covers its quarter
    gl_lds16(ag1,      &AB[0][0][2048 + w * 512]);
    gl_lds16(bg0,      &AB[0][1][w * 512]);
    gl_lds16(bg1,      &AB[0][1][2048 + w * 512]);
    gl_lds16(ag0 + 64, &AB[1][0][w * 512]);
    gl_lds16(ag1 + 64, &AB[1][0][2048 + w * 512]);
    gl_lds16(bg0 + 64, &AB[1][1][w * 512]);
    gl_lds16(bg1 + 64, &AB[1][1][2048 + w * 512]);

    constexpr int NT = 8;
    int buf = 0, sbuf = 2;
    for (int kt = 0; kt < NT; ++kt) {
        if (kt < NT - 1) asm volatile("s_waitcnt vmcnt(4)" ::: "memory");
        else             asm volatile("s_waitcnt vmcnt(0)" ::: "memory");
        __builtin_amdgcn_s_barrier();

        if (kt < NT - 2) {                         // stage step kt+2 (async)
            const int ko = (kt + 2) * 64;
            gl_lds16(ag0 + ko, &AB[sbuf][0][w * 512]);
            gl_lds16(ag1 + ko, &AB[sbuf][0][2048 + w * 512]);
            gl_lds16(bg0 + ko, &AB[sbuf][1][w * 512]);
            gl_lds16(bg1 + ko, &AB[sbuf][1][2048 + w * 512]);
        }
        const unsigned short* At = AB[buf][0];
        const unsigned short* Bt = AB[buf][1];

        #pragma unroll
        for (int kc = 0; kc < 2; ++kc) {
            const int fo = kc ? foff1 : foff0;
            bf16x8 a = *(const bf16x8*)(At + fo + w * 1024);
            #pragma unroll
            for (int n = 0; n < 4; ++n) {
                bf16x8 bb = *(const bf16x8*)(Bt + fo + n * 1024);
                acc[n] = __builtin_amdgcn_mfma_f32_16x16x32_bf16(a, bb, acc[n], 0, 0, 0);
            }
        }

        buf  = (buf  == 2) ? 0 : buf  + 1;
        sbuf = (sbuf == 2) ? 0 : sbuf + 1;
    }
    // C: col=lane&15 -> n-col = 16n+qh ; row = 4g+reg -> m = 16w+4g+r
    for (int n = 0; n < 4; ++n)
        for (int r = 0; r < 4; ++r)
            out[((size_t)(bs0 + 16*w + 4*g + r)) * 64 + 16*n + qh] = acc[n][r];
}

extern "C" void kernel_launch(void* const* d_in, const int* in_sizes, int n_in,
                              void* d_out, int out_size, void* d_ws, size_t ws_size,
                              hipStream_t stream)
{
    const float* x  = (const float*)d_in[0];
    const float* WQ = (const float*)d_in[1];
    const float* WK = (const float*)d_in[2];
    const float* WV = (const float*)d_in[3];
    const float* WO = (const float*)d_in[4];
    float* out = (float*)d_out;

    const size_t NQ = (size_t)Bn * Hn * Sn * LATn;     // 8,388,608
    char* p = (char*)d_ws;
    unsigned short* Qb  = (unsigned short*)p;           p += NQ * 2;            // 16MB
    unsigned short* Kb  = (unsigned short*)p;           p += NQ * 2;            // 16MB
    unsigned short* VT  = (unsigned short*)p;           p += NQ * 2;            // 16MB
    unsigned short* WT  = (unsigned short*)p;           p += ((size_t)Hn*192*Dn + 64*Dn) * 2;
    unsigned short* Ob  = (unsigned short*)p;                                   // 16MB
    unsigned short* WOT = WT + (size_t)Hn * 192 * Dn;
    unsigned short* Xb  = Ob;   // alias: Xb dead before flash writes Ob

    prep      <<<dim3(2248),          256, 0, stream>>>(x, WQ, WK, WV, WO, Xb, WT);
    qkv_mfma  <<<dim3(2048),          256, 0, stream>>>(Xb, WT, Qb, Kb, VT);
    flash_mfma<<<dim3(Sn/256, Bn*Hn), 512, 0, stream>>>(Qb, Kb, VT, Ob);
    out_mfma  <<<dim3(Bn*Sn/64),      256, 0, stream>>>(Ob, WOT, out);
}